// Round 2
// baseline (483.387 us; speedup 1.0000x reference)
//
#include <hip/hip_runtime.h>

#define T_STEPS 512
#define HID 128

// One block per batch row. 128 threads = 2 waves.
// Thread j owns output h[j]: W_hh row j lives in 128 VGPRs.
// Per step: h is exchanged via 1KB double-buffered LDS (1 barrier/step),
// broadcast across the wave with v_readlane (VALU pipe, no LDS-pipe bottleneck).
__global__ __launch_bounds__(128, 2)
void rnn_scan_kernel(const float* __restrict__ x,
                     const float* __restrict__ W_ih,
                     const float* __restrict__ W_hh,
                     const float* __restrict__ b_ih,
                     const float* __restrict__ b_hh,
                     const float* __restrict__ W_out,
                     const float* __restrict__ b_out,
                     float* __restrict__ y,
                     int T)
{
    const int b    = blockIdx.x;
    const int j    = threadIdx.x;      // 0..127 : which h element this thread produces
    const int lane = j & 63;
    const int wid  = j >> 6;           // 0: j in [0,64), 1: j in [64,128)

    __shared__ float hbuf[2][HID];
    __shared__ float red[2];

    // --- W_hh row j -> registers (fully unrolled, static indices => stays in VGPRs)
    float w[HID];
    const float4* wrow = reinterpret_cast<const float4*>(W_hh + j * HID);
    #pragma unroll
    for (int c = 0; c < HID / 4; ++c) {
        float4 v = wrow[c];
        w[4*c+0] = v.x; w[4*c+1] = v.y; w[4*c+2] = v.z; w[4*c+3] = v.w;
    }

    const float wih_j  = W_ih[j];
    const float bias_j = b_ih[j] + b_hh[j];
    const float* xrow  = x + (size_t)b * T;   // x is [B, T, 1]

    float hA = 0.0f;   // h[j] for this thread (h0 = 0)

    for (int t = 0; t < T; ++t) {
        // publish own half, fetch opposite half (double buffer -> 1 barrier/step)
        hbuf[t & 1][j] = hA;
        __syncthreads();
        const float hO = hbuf[t & 1][j ^ 64];

        // wave 0 lanes hold h[0..63] in hA, h[64..127] in hO; wave 1 swapped.
        const float src_lo = wid ? hO : hA;   // holds h[k],    k in [0,64)   at lane k
        const float src_hi = wid ? hA : hO;   // holds h[64+k], k in [0,64)   at lane k

        float acc0 = fmaf(xrow[t], wih_j, bias_j);
        float acc1 = 0.0f;

        #pragma unroll
        for (int k = 0; k < 64; ++k) {
            float s = __int_as_float(
                __builtin_amdgcn_readlane(__float_as_int(src_lo), k));
            if (k & 1) acc1 = fmaf(s, w[k], acc1);
            else       acc0 = fmaf(s, w[k], acc0);
        }
        #pragma unroll
        for (int k = 0; k < 64; ++k) {
            float s = __int_as_float(
                __builtin_amdgcn_readlane(__float_as_int(src_hi), k));
            if (k & 1) acc1 = fmaf(s, w[64 + k], acc1);
            else       acc0 = fmaf(s, w[64 + k], acc0);
        }

        const float a = acc0 + acc1;
        // tanh(a) = 1 - 2/(exp(2a)+1), exp via v_exp_f32
        const float e = __expf(2.0f * a);
        hA = 1.0f - __fdividef(2.0f, e + 1.0f);
        // e==inf -> 2/inf = 0 -> 1 ; e==0 -> 1-2 = -1 : saturation correct
    }

    // --- y[b] = sum_j W_out[j] * h_last[j] + b_out
    float v = hA * W_out[j];
    #pragma unroll
    for (int off = 32; off >= 1; off >>= 1)
        v += __shfl_xor(v, off, 64);
    if (lane == 0) red[wid] = v;
    __syncthreads();
    if (j == 0) y[b] = red[0] + red[1] + b_out[0];
}

extern "C" void kernel_launch(void* const* d_in, const int* in_sizes, int n_in,
                              void* d_out, int out_size, void* d_ws, size_t ws_size,
                              hipStream_t stream)
{
    const float* x     = (const float*)d_in[0];
    const float* W_ih  = (const float*)d_in[1];
    const float* W_hh  = (const float*)d_in[2];
    const float* b_ih  = (const float*)d_in[3];
    const float* b_hh  = (const float*)d_in[4];
    const float* W_out = (const float*)d_in[5];
    const float* b_out = (const float*)d_in[6];
    float* y = (float*)d_out;

    const int T = T_STEPS;
    const int B = in_sizes[0] / T;   // x has B*T*1 elements

    rnn_scan_kernel<<<B, HID, 0, stream>>>(x, W_ih, W_hh, b_ih, b_hh,
                                           W_out, b_out, y, T);
}

// Round 3
// 458.997 us; speedup vs baseline: 1.0531x; 1.0531x over previous
//
#include <hip/hip_runtime.h>

#define T_STEPS 512
#define HID 128

// One block per batch row. 128 threads = 2 waves.
// Thread j owns output h[j]: W_hh row j pinned in 128 VGPRs (asm register pin
// prevents the compiler from rematerializing the loads inside the t-loop —
// round 2 showed VGPR_Count=72, i.e. W_hh was being reloaded every step).
// Per step: h exchanged via 1KB double-buffered LDS (1 barrier/step),
// broadcast across the wave with v_readlane (VALU pipe).
__global__ __launch_bounds__(128, 2)
void rnn_scan_kernel(const float* __restrict__ x,
                     const float* __restrict__ W_ih,
                     const float* __restrict__ W_hh,
                     const float* __restrict__ b_ih,
                     const float* __restrict__ b_hh,
                     const float* __restrict__ W_out,
                     const float* __restrict__ b_out,
                     float* __restrict__ y,
                     int T)
{
    const int b    = blockIdx.x;
    const int j    = threadIdx.x;      // 0..127 : which h element this thread produces
    const int lane = j & 63;
    const int wid  = j >> 6;           // 0: j in [0,64), 1: j in [64,128)

    __shared__ float hbuf[2][HID];
    __shared__ float red[2];

    // --- W_hh row j -> registers
    float w[HID];
    const float4* wrow = reinterpret_cast<const float4*>(W_hh + j * HID);
    #pragma unroll
    for (int c = 0; c < HID / 4; ++c) {
        float4 v = wrow[c];
        w[4*c+0] = v.x; w[4*c+1] = v.y; w[4*c+2] = v.z; w[4*c+3] = v.w;
    }
    // Pin each w[c] to a VGPR: the empty asm writes the value, so the compiler
    // cannot rematerialize the global load inside the loop below.
    #pragma unroll
    for (int c = 0; c < HID; ++c)
        asm volatile("" : "+v"(w[c]));

    const float wih_j  = W_ih[j];
    const float bias_j = b_ih[j] + b_hh[j];
    const float* xrow  = x + (size_t)b * T;   // x is [B, T, 1]

    float hA = 0.0f;   // h[j] for this thread (h0 = 0)

    for (int t = 0; t < T; ++t) {
        // publish own half, fetch opposite half (double buffer -> 1 barrier/step)
        hbuf[t & 1][j] = hA;
        __syncthreads();
        const float hO = hbuf[t & 1][j ^ 64];

        // wave 0 lanes hold h[0..63] in hA, h[64..127] in hO; wave 1 swapped.
        const float src_lo = wid ? hO : hA;   // holds h[k],    k in [0,64)   at lane k
        const float src_hi = wid ? hA : hO;   // holds h[64+k], k in [0,64)   at lane k

        float acc0 = fmaf(xrow[t], wih_j, bias_j);
        float acc1 = 0.0f;

        #pragma unroll
        for (int k = 0; k < 64; ++k) {
            float s = __int_as_float(
                __builtin_amdgcn_readlane(__float_as_int(src_lo), k));
            if (k & 1) acc1 = fmaf(s, w[k], acc1);
            else       acc0 = fmaf(s, w[k], acc0);
        }
        #pragma unroll
        for (int k = 0; k < 64; ++k) {
            float s = __int_as_float(
                __builtin_amdgcn_readlane(__float_as_int(src_hi), k));
            if (k & 1) acc1 = fmaf(s, w[64 + k], acc1);
            else       acc0 = fmaf(s, w[64 + k], acc0);
        }

        const float a = acc0 + acc1;
        // tanh(a) = 1 - 2/(exp(2a)+1), exp via v_exp_f32
        const float e = __expf(2.0f * a);
        hA = 1.0f - __fdividef(2.0f, e + 1.0f);
        // e==inf -> 2/inf = 0 -> 1 ; e==0 -> 1-2 = -1 : saturation correct
    }

    // --- y[b] = sum_j W_out[j] * h_last[j] + b_out
    float v = hA * W_out[j];
    #pragma unroll
    for (int off = 32; off >= 1; off >>= 1)
        v += __shfl_xor(v, off, 64);
    if (lane == 0) red[wid] = v;
    __syncthreads();
    if (j == 0) y[b] = red[0] + red[1] + b_out[0];
}

extern "C" void kernel_launch(void* const* d_in, const int* in_sizes, int n_in,
                              void* d_out, int out_size, void* d_ws, size_t ws_size,
                              hipStream_t stream)
{
    const float* x     = (const float*)d_in[0];
    const float* W_ih  = (const float*)d_in[1];
    const float* W_hh  = (const float*)d_in[2];
    const float* b_ih  = (const float*)d_in[3];
    const float* b_hh  = (const float*)d_in[4];
    const float* W_out = (const float*)d_in[5];
    const float* b_out = (const float*)d_in[6];
    float* y = (float*)d_out;

    const int T = T_STEPS;
    const int B = in_sizes[0] / T;   // x has B*T*1 elements

    rnn_scan_kernel<<<B, HID, 0, stream>>>(x, W_ih, W_hh, b_ih, b_hh,
                                           W_out, b_out, y, T);
}